// Round 7
// baseline (1262.605 us; speedup 1.0000x reference)
//
#include <hip/hip_runtime.h>

#define Bq 8
#define Nq 4096
#define Dq 128
#define Hq 8
#define FFq 512
#define KNNq 16
#define Lq 2
#define DHq 16
#define EPSq 1e-5f

typedef _Float16 half4 __attribute__((ext_vector_type(4)));
typedef _Float16 half2t __attribute__((ext_vector_type(2)));
typedef float v4f __attribute__((ext_vector_type(4)));

static __device__ __forceinline__ half2t pkrtz(float a, float b) {
    return __builtin_bit_cast(half2t, __builtin_amdgcn_cvt_pkrtz(a, b));
}

// ---------------- fused prep: feat (f16) + weight fp32->f16 conversion ----------------
__global__ __launch_bounds__(256) void prep_kernel(const float* __restrict__ x,
                                                   const float* __restrict__ xyz_w,
                                                   const float* __restrict__ xyz_b,
                                                   const float* __restrict__ ohe_w,
                                                   const float* __restrict__ ohe_b,
                                                   _Float16* __restrict__ feat16,
                                                   const float* __restrict__ ipw,
                                                   const float* __restrict__ opw,
                                                   const float* __restrict__ l1w,
                                                   const float* __restrict__ l2w,
                                                   _Float16* __restrict__ wb) {
    int bid = blockIdx.x;
    if (bid < 16384) {
        int i = bid * 256 + threadIdx.x;
        int d = i & 127;
        int t = i >> 7;
        const float* xr = x + (size_t)t * 8;
        float s = xyz_b[d] + ohe_b[d];
        s += xr[0] * xyz_w[d * 3 + 0] + xr[1] * xyz_w[d * 3 + 1] + xr[2] * xyz_w[d * 3 + 2];
        s += xr[3] * ohe_w[d * 5 + 0] + xr[4] * ohe_w[d * 5 + 1] + xr[5] * ohe_w[d * 5 + 2]
           + xr[6] * ohe_w[d * 5 + 3] + xr[7] * ohe_w[d * 5 + 4];
        feat16[i] = (_Float16)s;
    } else {
        int i = (bid - 16384) * 256 + threadIdx.x;
        float v;
        if (i < 98304) v = ipw[i];
        else if (i < 131072) v = opw[i - 98304];
        else if (i < 262144) v = l1w[i - 131072];
        else v = l2w[i - 262144];
        wb[i] = (_Float16)v;
    }
}

// ---------------- KNN top-16 v8: batched bitonic selection ----------------
__global__ __launch_bounds__(512) void knn_kernel(const float* __restrict__ x, int* __restrict__ idx) {
    __shared__ __attribute__((aligned(16))) float sx[Nq];  // 16 KB
    __shared__ __attribute__((aligned(16))) float sy[Nq];  // 16 KB
    __shared__ __attribute__((aligned(16))) float sz[Nq];  // 16 KB -> 48 KB
    unsigned int (*md)[17] = (unsigned int (*)[17])sx;     // 512*17*4 = 34 KB, aliased (dead after scan)
    int b = blockIdx.y;
    int tid = threadIdx.x;
    for (int p = tid; p < Nq; p += 512) {
        const float* xr = x + ((size_t)b * Nq + p) * 8;
        sx[p] = xr[0]; sy[p] = xr[1]; sz[p] = xr[2];
    }
    __syncthreads();
    int qi = tid >> 3;   // 0..63 local query
    int part = tid & 7;
    int n = blockIdx.x * 64 + qi;
    float qx = sx[n], qy = sy[n], qz = sz[n];
    unsigned int top[16];
#pragma unroll
    for (int i = 0; i < 16; i++) top[i] = 0xFFFFFFFFu;
    int j0 = part * 512;
    int rot = part; // bank offset: partitions land on distinct banks, same-part lanes broadcast
    for (int bb = 0; bb < 32; bb++) {
        unsigned int c[16];
#pragma unroll
        for (int u = 0; u < 16; u++) {
            int j = j0 + ((bb * 16 + rot + u) & 511);
            float px = sx[j], py = sy[j], pz = sz[j];
            float dx = qx - px, dy = qy - py, dz = qz - pz;
            float d2 = fmaf(dx, dx, fmaf(dy, dy, dz * dz));
            unsigned int ky = (__float_as_uint(d2) & 0xFFFFF000u) | (unsigned int)j;
            c[u] = (j == n) ? 0xFFFFFFFFu : ky;
        }
        // bitonic sort c[16] ascending (80 compare-exchanges, 8-way ILP per substage)
#pragma unroll
        for (int kk = 2; kk <= 16; kk <<= 1) {
#pragma unroll
            for (int jj = 16 >> 1; jj > 0; jj >>= 1) {
                if (jj < kk) {
#pragma unroll
                    for (int i = 0; i < 16; i++) {
                        int l = i ^ jj;
                        if (l > i) {
                            unsigned int a0 = c[i], b0 = c[l];
                            unsigned int mn = a0 < b0 ? a0 : b0;
                            unsigned int mx = a0 < b0 ? b0 : a0;
                            bool up = ((i & kk) == 0);
                            c[i] = up ? mn : mx;
                            c[l] = up ? mx : mn;
                        }
                    }
                }
            }
        }
        // merge: keep smallest 16 of top ∪ c (bitonic lower half)
#pragma unroll
        for (int i = 0; i < 16; i++) {
            unsigned int a0 = top[i], b0 = c[15 - i];
            top[i] = a0 < b0 ? a0 : b0;
        }
        // half-cleaner cascade: sort the bitonic top[16] ascending
#pragma unroll
        for (int d = 8; d >= 1; d >>= 1) {
#pragma unroll
            for (int i = 0; i < 16; i++) {
                if ((i & d) == 0) {
                    int l = i | d;
                    unsigned int a0 = top[i], b0 = top[l];
                    top[i] = a0 < b0 ? a0 : b0;
                    top[l] = a0 < b0 ? b0 : a0;
                }
            }
        }
    }
    __syncthreads(); // all waves done scanning before md overwrites the scan buffer
#pragma unroll
    for (int i = 0; i < 16; i++) md[tid][i] = top[i];
    __syncthreads();
    if (part == 0) {
        unsigned int pall = 0;
        int* op = idx + ((size_t)b * Nq + n) * KNNq;
        int base_row = qi * 8;
#pragma unroll
        for (int s = 0; s < KNNq; s++) {
            unsigned int best = 0xFFFFFFFFu; int bp = 0;
#pragma unroll
            for (int p2 = 0; p2 < 8; p2++) {
                unsigned int ptr = (pall >> (p2 * 4)) & 15u;
                unsigned int v = md[base_row + p2][ptr];
                if (v < best) { best = v; bp = p2; }
            }
            op[s] = (int)(best & 4095u);
            pall += (1u << (bp * 4));
        }
    }
}

// ---------------- KNN attention: f16 gathers, f32 math, emits h16 only ----------------
__global__ __launch_bounds__(256, 4) void knn_attn_kernel(const _Float16* __restrict__ feat16,
                                                          const int* __restrict__ idx,
                                                          _Float16* __restrict__ h16) {
    int wave = threadIdx.x >> 6;
    int lane = threadIdx.x & 63;
    int token = blockIdx.x * 4 + wave;
    int b = token >> 12;
    half2t fh = ((const half2t*)(feat16 + (size_t)token * Dq))[lane];
    float2 f = make_float2((float)fh[0], (float)fh[1]);
    const int* ip = idx + (size_t)token * KNNq;
    int jj[KNNq];
#pragma unroll
    for (int k = 0; k < KNNq; k++) jj[k] = ip[k];
    float2 g[KNNq];
#pragma unroll
    for (int k = 0; k < KNNq; k++) {
        half2t gh = ((const half2t*)(feat16 + (((size_t)b << 12) + jj[k]) * Dq))[lane];
        g[k] = make_float2((float)gh[0], (float)gh[1]);
    }
    float sc[KNNq];
#pragma unroll
    for (int k = 0; k < KNNq; k++) {
        float p = f.x * g[k].x + f.y * g[k].y;
#pragma unroll
        for (int m = 1; m < 64; m <<= 1) p += __shfl_xor(p, m);
        sc[k] = p * 0.088388347648318447f; // 1/sqrt(128)
    }
    float mx = sc[0];
#pragma unroll
    for (int k = 1; k < KNNq; k++) mx = fmaxf(mx, sc[k]);
    float sum = 0.f;
#pragma unroll
    for (int k = 0; k < KNNq; k++) { sc[k] = __expf(sc[k] - mx); sum += sc[k]; }
    float inv = 1.f / sum;
    float o0 = 0.f, o1 = 0.f;
#pragma unroll
    for (int k = 0; k < KNNq; k++) { o0 += sc[k] * g[k].x; o1 += sc[k] * g[k].y; }
    ((half2t*)(h16 + (size_t)token * Dq))[lane] = pkrtz(o0 * inv, o1 * inv);
}

// ---------------- f16 MFMA GEMM, LDS-free ----------------
// MODE 2: qkv pack — Q (pre-scaled by 0.25*log2e) and K to pk[sel][bh][n][16],
// V TRANSPOSED to slot2 as Vt[bh][d][n].
template <int MODE>
__global__ __launch_bounds__(256) void hgemm_kernel(const _Float16* __restrict__ A,
                                                    const _Float16* __restrict__ W,
                                                    const float* __restrict__ bias,
                                                    void* __restrict__ Cout,
                                                    int M, int Nc, int K) {
    int tid = threadIdx.x;
    int lane = tid & 63, w = tid >> 6;
    int l15 = lane & 15, l4 = lane >> 4;
    int m0 = blockIdx.y * 64 + w * 16;
    int n0 = blockIdx.x * 64;
    const _Float16* Ap = A + (size_t)(m0 + l15) * K + l4 * 4;
    const _Float16* Wp = W + (size_t)(n0 + l15) * K + l4 * 4;
    v4f acc[4] = {{0.f, 0.f, 0.f, 0.f}, {0.f, 0.f, 0.f, 0.f}, {0.f, 0.f, 0.f, 0.f}, {0.f, 0.f, 0.f, 0.f}};
    for (int ks = 0; ks < K; ks += 16) {
        half4 af = *(const half4*)(Ap + ks);
#pragma unroll
        for (int nt = 0; nt < 4; nt++) {
            half4 wf = *(const half4*)(Wp + (size_t)nt * 16 * K + ks);
            acc[nt] = __builtin_amdgcn_mfma_f32_16x16x16f16(wf, af, acc[nt], 0, 0, 0);
        }
    }
    int m = m0 + l15;
#pragma unroll
    for (int nt = 0; nt < 4; nt++) {
        int nb = n0 + nt * 16 + l4 * 4;
        float4 bv = *(const float4*)(bias + nb);
        float v0 = acc[nt][0] + bv.x, v1 = acc[nt][1] + bv.y;
        float v2 = acc[nt][2] + bv.z, v3 = acc[nt][3] + bv.w;
        int n_base = n0 + nt * 16;
        int sel = n_base >> 7;
        if (MODE == 2 && sel == 0) {
            v0 *= 0.36067376f; v1 *= 0.36067376f; v2 *= 0.36067376f; v3 *= 0.36067376f;
        }
        half2t lo = pkrtz(v0, v1);
        half2t hi = pkrtz(v2, v3);
        half4 hv; hv[0] = lo[0]; hv[1] = lo[1]; hv[2] = hi[0]; hv[3] = hi[1];
        if (sel < 2) {
            int hh = (n_base >> 4) & 7;
            size_t base = (size_t)sel * (64ull * Nq * 16)
                        + ((size_t)((m >> 12) * 8 + hh)) * (Nq * 16)
                        + (size_t)(m & 4095) * 16 + l4 * 4;
            *(half4*)((_Float16*)Cout + base) = hv;
        } else {
            int hh = (n_base >> 4) & 7;
            size_t vb = 2ull * 64 * Nq * 16
                      + ((size_t)((m >> 12) * 8 + hh)) * (16 * Nq)
                      + (size_t)(m & 4095);
            _Float16* vp = (_Float16*)Cout + vb + (size_t)(l4 * 4) * Nq;
            vp[0 * Nq] = hv[0]; vp[1 * Nq] = hv[1]; vp[2 * Nq] = hv[2]; vp[3 * Nq] = hv[3];
        }
    }
}

// ---------------- flash v14: flash12 structure + T14 async-STAGE split.
// Global loads issued at iter top into REGISTERS; ds_write to LDS[nxt] AFTER the compute
// phase -> HBM latency hides under QK/exp/PV instead of stalling every wave at iter start.
// exp back on the transcendental pipe (v_exp_f32 co-issues; fast_exp2 measured worse). ----------------
__global__ __launch_bounds__(256) void flash14_kernel(const _Float16* __restrict__ pk,
                                                      _Float16* __restrict__ out16) {
    __shared__ _Float16 Ks[2][64 * 20];
    __shared__ _Float16 Vs[2][16 * 66];
    int tid = threadIdx.x;
    int lane = tid & 63, w = tid >> 6;
    int bh = blockIdx.y;
    const _Float16* Qb = pk + (size_t)bh * (Nq * 16);
    const _Float16* Kb = pk + (size_t)(64 + bh) * (Nq * 16);
    const _Float16* Vt = pk + 2ull * 64 * Nq * 16 + (size_t)bh * (16 * Nq);
    int q0 = blockIdx.x * 128 + w * 32;
    int l15 = lane & 15, l4 = lane >> 4;

    half4 qfA = *(const half4*)(Qb + (size_t)(q0 + l15) * 16 + l4 * 4);
    half4 qfB = *(const half4*)(Qb + (size_t)(q0 + 16 + l15) * 16 + l4 * 4);

    int sr = tid >> 2, sc = tid & 3;
    int vd = tid >> 4, vj = (tid & 15) * 4;
    const _Float16* Kg = Kb + (size_t)sr * 16 + sc * 4;
    const _Float16* Vg = Vt + (size_t)vd * Nq + vj;
    _Float16* KsW = Ks[0] + sr * 20 + sc * 4;   // this thread's staging slots
    _Float16* VsW = Vs[0] + vd * 66 + vj;
    const int KsHalf = 64 * 20, VsHalf = 16 * 66;

    *(half4*)(KsW) = *(const half4*)(Kg);
    *(half4*)(VsW) = *(const half4*)(Vg);
    __syncthreads();

    v4f oA = {0.f, 0.f, 0.f, 0.f}, oB = {0.f, 0.f, 0.f, 0.f};
    v4f lacA = {0.f, 0.f, 0.f, 0.f}, lacB = {0.f, 0.f, 0.f, 0.f};
    half4 ones;
    ones[0] = ones[1] = ones[2] = ones[3] = (_Float16)1.0f;

    for (int kt = 0; kt < Nq / 64; kt++) {
        int cur = kt & 1;
        // T14 phase 1: ISSUE next-tile loads into registers (no wait here)
        half4 kpre, vpre;
        if (kt < Nq / 64 - 1) {
            kpre = *(const half4*)(Kg + (size_t)(kt + 1) * 64 * 16);
            vpre = *(const half4*)(Vg + (kt + 1) * 64);
        }
        // compute phase on LDS[cur]
        const _Float16* Kc = Ks[cur];
        const _Float16* Vc = Vs[cur];
        half4 kf[4];
#pragma unroll
        for (int g = 0; g < 4; g++)
            kf[g] = *(const half4*)(Kc + (g * 16 + l15) * 20 + l4 * 4);
        v4f SA[4], SB[4];
#pragma unroll
        for (int g = 0; g < 4; g++) {
            SA[g] = __builtin_amdgcn_mfma_f32_16x16x16f16(kf[g], qfA, (v4f){0.f, 0.f, 0.f, 0.f}, 0, 0, 0);
            SB[g] = __builtin_amdgcn_mfma_f32_16x16x16f16(kf[g], qfB, (v4f){0.f, 0.f, 0.f, 0.f}, 0, 0, 0);
        }
        half4 PA[4], PB[4];
#pragma unroll
        for (int g = 0; g < 4; g++) {
            float a0 = __builtin_amdgcn_exp2f(SA[g][0]);
            float a1 = __builtin_amdgcn_exp2f(SA[g][1]);
            float a2 = __builtin_amdgcn_exp2f(SA[g][2]);
            float a3 = __builtin_amdgcn_exp2f(SA[g][3]);
            half2t alo = pkrtz(a0, a1);
            half2t ahi = pkrtz(a2, a3);
            PA[g][0] = alo[0]; PA[g][1] = alo[1]; PA[g][2] = ahi[0]; PA[g][3] = ahi[1];
            float b0 = __builtin_amdgcn_exp2f(SB[g][0]);
            float b1 = __builtin_amdgcn_exp2f(SB[g][1]);
            float b2 = __builtin_amdgcn_exp2f(SB[g][2]);
            float b3 = __builtin_amdgcn_exp2f(SB[g][3]);
            half2t blo = pkrtz(b0, b1);
            half2t bhi = pkrtz(b2, b3);
            PB[g][0] = blo[0]; PB[g][1] = blo[1]; PB[g][2] = bhi[0]; PB[g][3] = bhi[1];
        }
#pragma unroll
        for (int g = 0; g < 4; g++) {
            half4 vf = *(const half4*)(Vc + l15 * 66 + g * 16 + l4 * 4);
            lacA = __builtin_amdgcn_mfma_f32_16x16x16f16(ones, PA[g], lacA, 0, 0, 0);
            oA = __builtin_amdgcn_mfma_f32_16x16x16f16(vf, PA[g], oA, 0, 0, 0);
            lacB = __builtin_amdgcn_mfma_f32_16x16x16f16(ones, PB[g], lacB, 0, 0, 0);
            oB = __builtin_amdgcn_mfma_f32_16x16x16f16(vf, PB[g], oB, 0, 0, 0);
        }
        // T14 phase 2: write prefetched regs to LDS[nxt] AFTER compute (load latency hidden above)
        if (kt < Nq / 64 - 1) {
            int nxtoffK = (cur ^ 1) * KsHalf;
            int nxtoffV = (cur ^ 1) * VsHalf;
            *(half4*)(KsW + nxtoffK) = kpre;
            *(half4*)(VsW + nxtoffV) = vpre;
        }
        __syncthreads();
    }
    int b = bh >> 3, hh = bh & 7;
    {
        float inv = 1.f / lacA[0];
        int row = q0 + l15;
        half2t lo = pkrtz(oA[0] * inv, oA[1] * inv);
        half2t hi = pkrtz(oA[2] * inv, oA[3] * inv);
        half4 hv; hv[0] = lo[0]; hv[1] = lo[1]; hv[2] = hi[0]; hv[3] = hi[1];
        *(half4*)(out16 + ((size_t)(b * Nq + row)) * Dq + hh * 16 + l4 * 4) = hv;
    }
    {
        float inv = 1.f / lacB[0];
        int row = q0 + 16 + l15;
        half2t lo = pkrtz(oB[0] * inv, oB[1] * inv);
        half2t hi = pkrtz(oB[2] * inv, oB[3] * inv);
        half4 hv; hv[0] = lo[0]; hv[1] = lo[1]; hv[2] = hi[0]; hv[3] = hi[1];
        *(half4*)(out16 + ((size_t)(b * Nq + row)) * Dq + hh * 16 + l4 * 4) = hv;
    }
}

// ---------------- fused GEMM(Nc=128) + residual(h16) + LayerNorm -> h16 ----------------
__global__ __launch_bounds__(256) void hgemm_ln_kernel(const _Float16* __restrict__ A,
                                                       const _Float16* __restrict__ W,
                                                       const float* __restrict__ bias,
                                                       const float* __restrict__ lnw,
                                                       const float* __restrict__ lnb,
                                                       _Float16* __restrict__ h16,
                                                       int K) {
    int tid = threadIdx.x;
    int lane = tid & 63, w = tid >> 6;
    int l15 = lane & 15, l4 = lane >> 4;
    int m0 = blockIdx.x * 64 + w * 16;
    const _Float16* Ap = A + (size_t)(m0 + l15) * K + l4 * 4;
    const _Float16* Wp = W + (size_t)l15 * K + l4 * 4;
    v4f acc[8] = {};
    for (int ks = 0; ks < K; ks += 16) {
        half4 af = *(const half4*)(Ap + ks);
#pragma unroll
        for (int nt = 0; nt < 8; nt++) {
            half4 wf = *(const half4*)(Wp + (size_t)nt * 16 * K + ks);
            acc[nt] = __builtin_amdgcn_mfma_f32_16x16x16f16(wf, af, acc[nt], 0, 0, 0);
        }
    }
    int m = m0 + l15;
    float x[8][4];
    float psum = 0.f;
#pragma unroll
    for (int nt = 0; nt < 8; nt++) {
        int nb = nt * 16 + l4 * 4;
        float4 bv = *(const float4*)(bias + nb);
        half4 rv = *(const half4*)(h16 + (size_t)m * Dq + nb);
        x[nt][0] = acc[nt][0] + bv.x + (float)rv[0];
        x[nt][1] = acc[nt][1] + bv.y + (float)rv[1];
        x[nt][2] = acc[nt][2] + bv.z + (float)rv[2];
        x[nt][3] = acc[nt][3] + bv.w + (float)rv[3];
        psum += (x[nt][0] + x[nt][1]) + (x[nt][2] + x[nt][3]);
    }
    psum += __shfl_xor(psum, 16);
    psum += __shfl_xor(psum, 32);
    float mean = psum * (1.f / 128.f);
    float vsum = 0.f;
#pragma unroll
    for (int nt = 0; nt < 8; nt++)
#pragma unroll
        for (int r = 0; r < 4; r++) {
            x[nt][r] -= mean;
            vsum += x[nt][r] * x[nt][r];
        }
    vsum += __shfl_xor(vsum, 16);
    vsum += __shfl_xor(vsum, 32);
    float inv = rsqrtf(vsum * (1.f / 128.f) + EPSq);
#pragma unroll
    for (int nt = 0; nt < 8; nt++) {
        int nb = nt * 16 + l4 * 4;
        float4 wv = *(const float4*)(lnw + nb);
        float4 bb = *(const float4*)(lnb + nb);
        float y0 = x[nt][0] * inv * wv.x + bb.x;
        float y1 = x[nt][1] * inv * wv.y + bb.y;
        float y2 = x[nt][2] * inv * wv.z + bb.z;
        float y3 = x[nt][3] * inv * wv.w + bb.w;
        half2t lo = pkrtz(y0, y1);
        half2t hi = pkrtz(y2, y3);
        half4 hv2; hv2[0] = lo[0]; hv2[1] = lo[1]; hv2[2] = hi[0]; hv2[3] = hi[1];
        *(half4*)(h16 + (size_t)m * Dq + nb) = hv2;
    }
}

// ---------------- fused FFN (+ LN). LAST=1: emit per-wave column partial sums for pooling ----------------
template <int LAST>
__global__ __launch_bounds__(256) void ffn_kernel(const _Float16* __restrict__ h16in,
                                                  const _Float16* __restrict__ W1,
                                                  const float* __restrict__ b1,
                                                  const _Float16* __restrict__ W2,
                                                  const float* __restrict__ b2,
                                                  const float* __restrict__ lnw,
                                                  const float* __restrict__ lnb,
                                                  _Float16* __restrict__ h16,
                                                  float* __restrict__ part) {
    int tid = threadIdx.x;
    int lane = tid & 63, w = tid >> 6;
    int l15 = lane & 15, l4 = lane >> 4;
    int m0 = blockIdx.x * 64 + w * 16;
    int m = m0 + l15;
    const _Float16* Ap = h16in + (size_t)m * Dq + l4 * 4;
    half4 afr[8];
#pragma unroll
    for (int t = 0; t < 8; t++) afr[t] = *(const half4*)(Ap + t * 16);
    half4 mid[32];
#pragma unroll
    for (int c = 0; c < 8; c++) {
        v4f acc[4] = {};
#pragma unroll
        for (int t = 0; t < 8; t++) {
#pragma unroll
            for (int nt = 0; nt < 4; nt++) {
                half4 wf = *(const half4*)(W1 + (size_t)(c * 64 + nt * 16 + l15) * 128 + t * 16 + l4 * 4);
                acc[nt] = __builtin_amdgcn_mfma_f32_16x16x16f16(wf, afr[t], acc[nt], 0, 0, 0);
            }
        }
#pragma unroll
        for (int nt = 0; nt < 4; nt++) {
            float4 bv = *(const float4*)(b1 + c * 64 + nt * 16 + l4 * 4);
            float v0 = fmaxf(acc[nt][0] + bv.x, 0.f);
            float v1 = fmaxf(acc[nt][1] + bv.y, 0.f);
            float v2 = fmaxf(acc[nt][2] + bv.z, 0.f);
            float v3 = fmaxf(acc[nt][3] + bv.w, 0.f);
            half2t lo = pkrtz(v0, v1), hi = pkrtz(v2, v3);
            half4 hv; hv[0] = lo[0]; hv[1] = lo[1]; hv[2] = hi[0]; hv[3] = hi[1];
            mid[c * 4 + nt] = hv;
        }
    }
    v4f acc8[8] = {};
#pragma unroll 4
    for (int t = 0; t < 32; t++) {
#pragma unroll
        for (int nt = 0; nt < 8; nt++) {
            half4 wf = *(const half4*)(W2 + (size_t)(nt * 16 + l15) * 512 + t * 16 + l4 * 4);
            acc8[nt] = __builtin_amdgcn_mfma_f32_16x16x16f16(wf, mid[t], acc8[nt], 0, 0, 0);
        }
    }
    float x[8][4];
    float psum = 0.f;
#pragma unroll
    for (int nt = 0; nt < 8; nt++) {
        int nb = nt * 16 + l4 * 4;
        float4 bv = *(const float4*)(b2 + nb);
        x[nt][0] = acc8[nt][0] + bv.x + (float)afr[nt][0];
        x[nt][1] = acc8[nt][1] + bv.y + (float)afr[nt][1];
        x[nt][2] = acc8[nt][2] + bv.z + (float)afr[nt][2];
        x[nt][3] = acc8[nt][3] + bv.w + (float)afr[nt][3];
        psum += (x[nt][0] + x[nt][1]) + (x[nt][2] + x[nt][3]);
    }
    psum += __shfl_xor(psum, 16);
    psum += __shfl_xor(psum, 32);
    float mean = psum * (1.f / 128.f);
    float vsum = 0.f;
#pragma unroll
    for (int nt = 0; nt < 8; nt++)
#pragma unroll
        for (int r = 0; r < 4; r++) {
            x[nt][r] -= mean;
            vsum += x[nt][r] * x[nt][r];
        }
    vsum += __shfl_xor(vsum, 16);
    vsum += __shfl_xor(vsum, 32);
    float inv = rsqrtf(vsum * (1.f / 128.f) + EPSq);
#pragma unroll
    for (int nt = 0; nt < 8; nt++) {
        int nb = nt * 16 + l4 * 4;
        float4 wv = *(const float4*)(lnw + nb);
        float4 bb = *(const float4*)(lnb + nb);
        x[nt][0] = x[nt][0] * inv * wv.x + bb.x;
        x[nt][1] = x[nt][1] * inv * wv.y + bb.y;
        x[nt][2] = x[nt][2] * inv * wv.z + bb.z;
        x[nt][3] = x[nt][3] * inv * wv.w + bb.w;
        if (!LAST) {
            half2t lo = pkrtz(x[nt][0], x[nt][1]);
            half2t hi = pkrtz(x[nt][2], x[nt][3]);
            half4 hv2; hv2[0] = lo[0]; hv2[1] = lo[1]; hv2[2] = hi[0]; hv2[3] = hi[1];
            *(half4*)(h16 + (size_t)m * Dq + nb) = hv2;
        }
    }
    if (LAST) {
#pragma unroll
        for (int nt = 0; nt < 8; nt++)
#pragma unroll
            for (int r = 0; r < 4; r++) {
                float v = x[nt][r];
                v += __shfl_xor(v, 1);
                v += __shfl_xor(v, 2);
                v += __shfl_xor(v, 4);
                v += __shfl_xor(v, 8);
                x[nt][r] = v;
            }
        if (l15 == 0) {
            float* pp = part + ((size_t)blockIdx.x * 4 + w) * Dq;
#pragma unroll
            for (int nt = 0; nt < 8; nt++)
#pragma unroll
                for (int r = 0; r < 4; r++)
                    pp[nt * 16 + l4 * 4 + r] = x[nt][r];
        }
    }
}

// ---------------- head: pooled = mean over N via 256 wave-partials; MLP + sigmoid ----------------
__global__ __launch_bounds__(512) void head_kernel(const float* __restrict__ part,
                                                   const float* __restrict__ fc1_w, const float* __restrict__ fc1_b,
                                                   const float* __restrict__ fc2_w, const float* __restrict__ fc2_b,
                                                   float* __restrict__ out) {
    __shared__ float psh[Dq];
    __shared__ float red[512];
    int b = blockIdx.x, f = threadIdx.x;
    if (f < Dq) {
        float s = 0.f;
        for (int c = 0; c < 256; c++) s += part[((size_t)b * 256 + c) * Dq + f];
        psh[f] = s * (1.f / 4096.f);
    }
    __syncthreads();
    const float* wr = fc1_w + (size_t)f * Dq;
    float s = fc1_b[f];
    for (int d = 0; d < Dq; d++) s += psh[d] * wr[d];
    red[f] = fmaxf(s, 0.f) * fc2_w[f];
    __syncthreads();
    for (int st = 256; st > 0; st >>= 1) {
        if (f < st) red[f] += red[f + st];
        __syncthreads();
    }
    if (f == 0) out[b] = 1.f / (1.f + __expf(-(red[0] + fc2_b[0])));
}

extern "C" void kernel_launch(void* const* d_in, const int* in_sizes, int n_in,
                              void* d_out, int out_size, void* d_ws, size_t ws_size,
                              hipStream_t stream) {
    const float* x        = (const float*)d_in[0];
    const float* xyz_w    = (const float*)d_in[1];
    const float* xyz_b    = (const float*)d_in[2];
    const float* ohe_w    = (const float*)d_in[3];
    const float* ohe_b    = (const float*)d_in[4];
    const float* in_proj_w  = (const float*)d_in[5];
    const float* in_proj_b  = (const float*)d_in[6];
    const float* out_proj_w = (const float*)d_in[7];
    const float* out_proj_b = (const float*)d_in[8];
    const float* ln1_w    = (const float*)d_in[9];
    const float* ln1_b    = (const float*)d_in[10];
    const float* lin1_w   = (const float*)d_in[11];
    const float* lin1_b   = (const float*)d_in[12];
    const float* lin2_w   = (const float*)d_in[13];
    const float* lin2_b   = (const float*)d_in[14];
    const float* ln2_w    = (const float*)d_in[15];
    const float* ln2_b    = (const float*)d_in[16];
    const float* fc1_w    = (const float*)d_in[17];
    const float* fc1_b    = (const float*)d_in[18];
    const float* fc2_w    = (const float*)d_in[19];
    const float* fc2_b    = (const float*)d_in[20];
    float* outp = (float*)d_out;

    char* ws = (char*)d_ws;
    size_t off = 0;
    auto alloc = [&](size_t bytes) { void* p = ws + off; off += (bytes + 255) & ~255ULL; return p; };
    _Float16*  feat16 = (_Float16*)alloc((size_t)Bq * Nq * Dq * 2);
    _Float16*  h16    = (_Float16*)alloc((size_t)Bq * Nq * Dq * 2);
    _Float16*  abuf16 = (_Float16*)alloc((size_t)Bq * Nq * Dq * 2);
    _Float16*  pkb    = (_Float16*)alloc(3ull * 64 * Nq * 16 * 2);
    _Float16*  wb     = (_Float16*)alloc(393216ull * 2);
    int*       idx    = (int*)alloc((size_t)Bq * Nq * KNNq * 4);
    float*     part   = (float*)alloc(2048ull * Dq * 4);
    if (off > ws_size) return;

    const _Float16* wip16 = wb;
    const _Float16* wop16 = wb + 98304;
    const _Float16* wl116 = wb + 131072;
    const _Float16* wl216 = wb + 262144;

    int M = Bq * Nq;

    prep_kernel<<<16384 + 1536, 256, 0, stream>>>(x, xyz_w, xyz_b, ohe_w, ohe_b, feat16,
                                                  in_proj_w, out_proj_w, lin1_w, lin2_w, wb);
    knn_kernel<<<dim3(Nq / 64, Bq), 512, 0, stream>>>(x, idx);
    knn_attn_kernel<<<M / 4, 256, 0, stream>>>(feat16, idx, h16);

    for (int l = 0; l < Lq; l++) {
        hgemm_kernel<2><<<dim3(384 / 64, M / 64), 256, 0, stream>>>(
            h16, wip16 + (size_t)l * 384 * 128, in_proj_b + l * 384, pkb, M, 384, 128);
        flash14_kernel<<<dim3(Nq / 128, Bq * Hq), 256, 0, stream>>>(pkb, abuf16);
        hgemm_ln_kernel<<<M / 64, 256, 0, stream>>>(
            abuf16, wop16 + (size_t)l * 128 * 128, out_proj_b + l * 128,
            ln1_w + l * 128, ln1_b + l * 128, h16, 128);
        if (l == 0) {
            ffn_kernel<0><<<M / 64, 256, 0, stream>>>(
                h16, wl116, lin1_b, wl216, lin2_b, ln2_w, ln2_b, h16, part);
        } else {
            ffn_kernel<1><<<M / 64, 256, 0, stream>>>(
                h16, wl116 + (size_t)l * 512 * 128, lin1_b + l * 512,
                wl216 + (size_t)l * 128 * 512, lin2_b + l * 128,
                ln2_w + l * 128, ln2_b + l * 128, h16, part);
        }
    }

    head_kernel<<<Bq, 512, 0, stream>>>(part, fc1_w, fc1_b, fc2_w, fc2_b, outp);
}

// Round 8
// 1216.968 us; speedup vs baseline: 1.0375x; 1.0375x over previous
//
#include <hip/hip_runtime.h>

#define Bq 8
#define Nq 4096
#define Dq 128
#define Hq 8
#define FFq 512
#define KNNq 16
#define Lq 2
#define DHq 16
#define EPSq 1e-5f

typedef _Float16 half4 __attribute__((ext_vector_type(4)));
typedef _Float16 half2t __attribute__((ext_vector_type(2)));
typedef float v4f __attribute__((ext_vector_type(4)));

static __device__ __forceinline__ half2t pkrtz(float a, float b) {
    return __builtin_bit_cast(half2t, __builtin_amdgcn_cvt_pkrtz(a, b));
}

// ---------------- fused prep: feat (f16) + weight fp32->f16 conversion ----------------
__global__ __launch_bounds__(256) void prep_kernel(const float* __restrict__ x,
                                                   const float* __restrict__ xyz_w,
                                                   const float* __restrict__ xyz_b,
                                                   const float* __restrict__ ohe_w,
                                                   const float* __restrict__ ohe_b,
                                                   _Float16* __restrict__ feat16,
                                                   const float* __restrict__ ipw,
                                                   const float* __restrict__ opw,
                                                   const float* __restrict__ l1w,
                                                   const float* __restrict__ l2w,
                                                   _Float16* __restrict__ wb) {
    int bid = blockIdx.x;
    if (bid < 16384) {
        int i = bid * 256 + threadIdx.x;
        int d = i & 127;
        int t = i >> 7;
        const float* xr = x + (size_t)t * 8;
        float s = xyz_b[d] + ohe_b[d];
        s += xr[0] * xyz_w[d * 3 + 0] + xr[1] * xyz_w[d * 3 + 1] + xr[2] * xyz_w[d * 3 + 2];
        s += xr[3] * ohe_w[d * 5 + 0] + xr[4] * ohe_w[d * 5 + 1] + xr[5] * ohe_w[d * 5 + 2]
           + xr[6] * ohe_w[d * 5 + 3] + xr[7] * ohe_w[d * 5 + 4];
        feat16[i] = (_Float16)s;
    } else {
        int i = (bid - 16384) * 256 + threadIdx.x;
        float v;
        if (i < 98304) v = ipw[i];
        else if (i < 131072) v = opw[i - 98304];
        else if (i < 262144) v = l1w[i - 131072];
        else v = l2w[i - 262144];
        wb[i] = (_Float16)v;
    }
}

// ---------------- KNN top-16 v8: batched bitonic selection ----------------
__global__ __launch_bounds__(512) void knn_kernel(const float* __restrict__ x, int* __restrict__ idx) {
    __shared__ __attribute__((aligned(16))) float sx[Nq];  // 16 KB
    __shared__ __attribute__((aligned(16))) float sy[Nq];  // 16 KB
    __shared__ __attribute__((aligned(16))) float sz[Nq];  // 16 KB -> 48 KB
    unsigned int (*md)[17] = (unsigned int (*)[17])sx;     // 512*17*4 = 34 KB, aliased (dead after scan)
    int b = blockIdx.y;
    int tid = threadIdx.x;
    for (int p = tid; p < Nq; p += 512) {
        const float* xr = x + ((size_t)b * Nq + p) * 8;
        sx[p] = xr[0]; sy[p] = xr[1]; sz[p] = xr[2];
    }
    __syncthreads();
    int qi = tid >> 3;   // 0..63 local query
    int part = tid & 7;
    int n = blockIdx.x * 64 + qi;
    float qx = sx[n], qy = sy[n], qz = sz[n];
    unsigned int top[16];
#pragma unroll
    for (int i = 0; i < 16; i++) top[i] = 0xFFFFFFFFu;
    int j0 = part * 512;
    int rot = part; // bank offset: partitions land on distinct banks, same-part lanes broadcast
    for (int bb = 0; bb < 32; bb++) {
        unsigned int c[16];
#pragma unroll
        for (int u = 0; u < 16; u++) {
            int j = j0 + ((bb * 16 + rot + u) & 511);
            float px = sx[j], py = sy[j], pz = sz[j];
            float dx = qx - px, dy = qy - py, dz = qz - pz;
            float d2 = fmaf(dx, dx, fmaf(dy, dy, dz * dz));
            unsigned int ky = (__float_as_uint(d2) & 0xFFFFF000u) | (unsigned int)j;
            c[u] = (j == n) ? 0xFFFFFFFFu : ky;
        }
        // bitonic sort c[16] ascending (80 compare-exchanges, 8-way ILP per substage)
#pragma unroll
        for (int kk = 2; kk <= 16; kk <<= 1) {
#pragma unroll
            for (int jj = 16 >> 1; jj > 0; jj >>= 1) {
                if (jj < kk) {
#pragma unroll
                    for (int i = 0; i < 16; i++) {
                        int l = i ^ jj;
                        if (l > i) {
                            unsigned int a0 = c[i], b0 = c[l];
                            unsigned int mn = a0 < b0 ? a0 : b0;
                            unsigned int mx = a0 < b0 ? b0 : a0;
                            bool up = ((i & kk) == 0);
                            c[i] = up ? mn : mx;
                            c[l] = up ? mx : mn;
                        }
                    }
                }
            }
        }
        // merge: keep smallest 16 of top ∪ c (bitonic lower half)
#pragma unroll
        for (int i = 0; i < 16; i++) {
            unsigned int a0 = top[i], b0 = c[15 - i];
            top[i] = a0 < b0 ? a0 : b0;
        }
        // half-cleaner cascade: sort the bitonic top[16] ascending
#pragma unroll
        for (int d = 8; d >= 1; d >>= 1) {
#pragma unroll
            for (int i = 0; i < 16; i++) {
                if ((i & d) == 0) {
                    int l = i | d;
                    unsigned int a0 = top[i], b0 = top[l];
                    top[i] = a0 < b0 ? a0 : b0;
                    top[l] = a0 < b0 ? b0 : a0;
                }
            }
        }
    }
    __syncthreads(); // all waves done scanning before md overwrites the scan buffer
#pragma unroll
    for (int i = 0; i < 16; i++) md[tid][i] = top[i];
    __syncthreads();
    if (part == 0) {
        unsigned int pall = 0;
        int* op = idx + ((size_t)b * Nq + n) * KNNq;
        int base_row = qi * 8;
#pragma unroll
        for (int s = 0; s < KNNq; s++) {
            unsigned int best = 0xFFFFFFFFu; int bp = 0;
#pragma unroll
            for (int p2 = 0; p2 < 8; p2++) {
                unsigned int ptr = (pall >> (p2 * 4)) & 15u;
                unsigned int v = md[base_row + p2][ptr];
                if (v < best) { best = v; bp = p2; }
            }
            op[s] = (int)(best & 4095u);
            pall += (1u << (bp * 4));
        }
    }
}

// ---------------- KNN attention: f16 gathers, f32 math, emits h16 only ----------------
__global__ __launch_bounds__(256, 4) void knn_attn_kernel(const _Float16* __restrict__ feat16,
                                                          const int* __restrict__ idx,
                                                          _Float16* __restrict__ h16) {
    int wave = threadIdx.x >> 6;
    int lane = threadIdx.x & 63;
    int token = blockIdx.x * 4 + wave;
    int b = token >> 12;
    half2t fh = ((const half2t*)(feat16 + (size_t)token * Dq))[lane];
    float2 f = make_float2((float)fh[0], (float)fh[1]);
    const int* ip = idx + (size_t)token * KNNq;
    int jj[KNNq];
#pragma unroll
    for (int k = 0; k < KNNq; k++) jj[k] = ip[k];
    float2 g[KNNq];
#pragma unroll
    for (int k = 0; k < KNNq; k++) {
        half2t gh = ((const half2t*)(feat16 + (((size_t)b << 12) + jj[k]) * Dq))[lane];
        g[k] = make_float2((float)gh[0], (float)gh[1]);
    }
    float sc[KNNq];
#pragma unroll
    for (int k = 0; k < KNNq; k++) {
        float p = f.x * g[k].x + f.y * g[k].y;
#pragma unroll
        for (int m = 1; m < 64; m <<= 1) p += __shfl_xor(p, m);
        sc[k] = p * 0.088388347648318447f; // 1/sqrt(128)
    }
    float mx = sc[0];
#pragma unroll
    for (int k = 1; k < KNNq; k++) mx = fmaxf(mx, sc[k]);
    float sum = 0.f;
#pragma unroll
    for (int k = 0; k < KNNq; k++) { sc[k] = __expf(sc[k] - mx); sum += sc[k]; }
    float inv = 1.f / sum;
    float o0 = 0.f, o1 = 0.f;
#pragma unroll
    for (int k = 0; k < KNNq; k++) { o0 += sc[k] * g[k].x; o1 += sc[k] * g[k].y; }
    ((half2t*)(h16 + (size_t)token * Dq))[lane] = pkrtz(o0 * inv, o1 * inv);
}

// ---------------- f16 MFMA GEMM, LDS-free ----------------
// MODE 2: qkv pack — Q (pre-scaled by 0.25*log2e) and K to pk[sel][bh][n][16],
// V TRANSPOSED to slot2 as Vt[bh][d][n].
template <int MODE>
__global__ __launch_bounds__(256) void hgemm_kernel(const _Float16* __restrict__ A,
                                                    const _Float16* __restrict__ W,
                                                    const float* __restrict__ bias,
                                                    void* __restrict__ Cout,
                                                    int M, int Nc, int K) {
    int tid = threadIdx.x;
    int lane = tid & 63, w = tid >> 6;
    int l15 = lane & 15, l4 = lane >> 4;
    int m0 = blockIdx.y * 64 + w * 16;
    int n0 = blockIdx.x * 64;
    const _Float16* Ap = A + (size_t)(m0 + l15) * K + l4 * 4;
    const _Float16* Wp = W + (size_t)(n0 + l15) * K + l4 * 4;
    v4f acc[4] = {{0.f, 0.f, 0.f, 0.f}, {0.f, 0.f, 0.f, 0.f}, {0.f, 0.f, 0.f, 0.f}, {0.f, 0.f, 0.f, 0.f}};
    for (int ks = 0; ks < K; ks += 16) {
        half4 af = *(const half4*)(Ap + ks);
#pragma unroll
        for (int nt = 0; nt < 4; nt++) {
            half4 wf = *(const half4*)(Wp + (size_t)nt * 16 * K + ks);
            acc[nt] = __builtin_amdgcn_mfma_f32_16x16x16f16(wf, af, acc[nt], 0, 0, 0);
        }
    }
    int m = m0 + l15;
#pragma unroll
    for (int nt = 0; nt < 4; nt++) {
        int nb = n0 + nt * 16 + l4 * 4;
        float4 bv = *(const float4*)(bias + nb);
        float v0 = acc[nt][0] + bv.x, v1 = acc[nt][1] + bv.y;
        float v2 = acc[nt][2] + bv.z, v3 = acc[nt][3] + bv.w;
        int n_base = n0 + nt * 16;
        int sel = n_base >> 7;
        if (MODE == 2 && sel == 0) {
            v0 *= 0.36067376f; v1 *= 0.36067376f; v2 *= 0.36067376f; v3 *= 0.36067376f;
        }
        half2t lo = pkrtz(v0, v1);
        half2t hi = pkrtz(v2, v3);
        half4 hv; hv[0] = lo[0]; hv[1] = lo[1]; hv[2] = hi[0]; hv[3] = hi[1];
        if (sel < 2) {
            int hh = (n_base >> 4) & 7;
            size_t base = (size_t)sel * (64ull * Nq * 16)
                        + ((size_t)((m >> 12) * 8 + hh)) * (Nq * 16)
                        + (size_t)(m & 4095) * 16 + l4 * 4;
            *(half4*)((_Float16*)Cout + base) = hv;
        } else {
            int hh = (n_base >> 4) & 7;
            size_t vb = 2ull * 64 * Nq * 16
                      + ((size_t)((m >> 12) * 8 + hh)) * (16 * Nq)
                      + (size_t)(m & 4095);
            _Float16* vp = (_Float16*)Cout + vb + (size_t)(l4 * 4) * Nq;
            vp[0 * Nq] = hv[0]; vp[1 * Nq] = hv[1]; vp[2 * Nq] = hv[2]; vp[3 * Nq] = hv[3];
        }
    }
}

// ---------------- flash v16: flash12's exact schedule (top-staging, ones-lac, v_exp),
// single structural change: 128-key tiles as two unrolled 64-key sub-rounds per barrier.
// Halves barrier count (64->32) and prefetch-chunk count -> attacks the measured 29% both-pipes-idle stall. ----------------
__global__ __launch_bounds__(256) void flash16_kernel(const _Float16* __restrict__ pk,
                                                      _Float16* __restrict__ out16) {
    __shared__ _Float16 Ks[2][128 * 20];  // 10240 B, row stride 40 B -> conflict-free kf reads
    __shared__ _Float16 Vs[2][16 * 130];  // 8320 B, row stride 260 B (65 banks ~ 1) -> conflict-free
    int tid = threadIdx.x;
    int lane = tid & 63, w = tid >> 6;
    int bh = blockIdx.y;
    const _Float16* Qb = pk + (size_t)bh * (Nq * 16);
    const _Float16* Kb = pk + (size_t)(64 + bh) * (Nq * 16);
    const _Float16* Vt = pk + 2ull * 64 * Nq * 16 + (size_t)bh * (16 * Nq);
    int q0 = blockIdx.x * 128 + w * 32;
    int l15 = lane & 15, l4 = lane >> 4;

    half4 qfA = *(const half4*)(Qb + (size_t)(q0 + l15) * 16 + l4 * 4);
    half4 qfB = *(const half4*)(Qb + (size_t)(q0 + 16 + l15) * 16 + l4 * 4);

    int sr = tid >> 2, sc = tid & 3;         // K rows sr and sr+64
    int vd = tid >> 4, vj = (tid & 15) * 4;  // V cols vj and vj+64
    const _Float16* Kg = Kb + (size_t)sr * 16 + sc * 4;
    const _Float16* Vg = Vt + (size_t)vd * Nq + vj;

    *(half4*)(Ks[0] + sr * 20 + sc * 4) = *(const half4*)(Kg);
    *(half4*)(Ks[0] + (sr + 64) * 20 + sc * 4) = *(const half4*)(Kg + 64 * 16);
    *(half4*)(Vs[0] + vd * 130 + vj) = *(const half4*)(Vg);
    *(half4*)(Vs[0] + vd * 130 + vj + 64) = *(const half4*)(Vg + 64);
    __syncthreads();

    v4f oA = {0.f, 0.f, 0.f, 0.f}, oB = {0.f, 0.f, 0.f, 0.f};
    v4f lacA = {0.f, 0.f, 0.f, 0.f}, lacB = {0.f, 0.f, 0.f, 0.f};
    half4 ones;
    ones[0] = ones[1] = ones[2] = ones[3] = (_Float16)1.0f;

    const int NT = Nq / 128;  // 32
    for (int kt = 0; kt < NT; kt++) {
        int cur = kt & 1, nxt = cur ^ 1;
        if (kt < NT - 1) {
            const _Float16* kg = Kg + (size_t)(kt + 1) * (128 * 16);
            const _Float16* vg = Vg + (kt + 1) * 128;
            *(half4*)(Ks[nxt] + sr * 20 + sc * 4) = *(const half4*)(kg);
            *(half4*)(Ks[nxt] + (sr + 64) * 20 + sc * 4) = *(const half4*)(kg + 64 * 16);
            *(half4*)(Vs[nxt] + vd * 130 + vj) = *(const half4*)(vg);
            *(half4*)(Vs[nxt] + vd * 130 + vj + 64) = *(const half4*)(vg + 64);
        }
#pragma unroll
        for (int hf = 0; hf < 2; hf++) {
            const _Float16* Kc = Ks[cur] + hf * (64 * 20);
            const _Float16* Vc = Vs[cur] + hf * 64;
            half4 kf[4];
#pragma unroll
            for (int g = 0; g < 4; g++)
                kf[g] = *(const half4*)(Kc + (g * 16 + l15) * 20 + l4 * 4);
            v4f SA[4], SB[4];
#pragma unroll
            for (int g = 0; g < 4; g++) {
                SA[g] = __builtin_amdgcn_mfma_f32_16x16x16f16(kf[g], qfA, (v4f){0.f, 0.f, 0.f, 0.f}, 0, 0, 0);
                SB[g] = __builtin_amdgcn_mfma_f32_16x16x16f16(kf[g], qfB, (v4f){0.f, 0.f, 0.f, 0.f}, 0, 0, 0);
            }
            half4 PA[4], PB[4];
#pragma unroll
            for (int g = 0; g < 4; g++) {
                float a0 = __builtin_amdgcn_exp2f(SA[g][0]);
                float a1 = __builtin_amdgcn_exp2f(SA[g][1]);
                float a2 = __builtin_amdgcn_exp2f(SA[g][2]);
                float a3 = __builtin_amdgcn_exp2f(SA[g][3]);
                half2t alo = pkrtz(a0, a1);
                half2t ahi = pkrtz(a2, a3);
                PA[g][0] = alo[0]; PA[g][1] = alo[1]; PA[g][2] = ahi[0]; PA[g][3] = ahi[1];
                float b0 = __builtin_amdgcn_exp2f(SB[g][0]);
                float b1 = __builtin_amdgcn_exp2f(SB[g][1]);
                float b2 = __builtin_amdgcn_exp2f(SB[g][2]);
                float b3 = __builtin_amdgcn_exp2f(SB[g][3]);
                half2t blo = pkrtz(b0, b1);
                half2t bhi = pkrtz(b2, b3);
                PB[g][0] = blo[0]; PB[g][1] = blo[1]; PB[g][2] = bhi[0]; PB[g][3] = bhi[1];
            }
#pragma unroll
            for (int g = 0; g < 4; g++) {
                half4 vf = *(const half4*)(Vc + l15 * 130 + g * 16 + l4 * 4);
                lacA = __builtin_amdgcn_mfma_f32_16x16x16f16(ones, PA[g], lacA, 0, 0, 0);
                oA = __builtin_amdgcn_mfma_f32_16x16x16f16(vf, PA[g], oA, 0, 0, 0);
                lacB = __builtin_amdgcn_mfma_f32_16x16x16f16(ones, PB[g], lacB, 0, 0, 0);
                oB = __builtin_amdgcn_mfma_f32_16x16x16f16(vf, PB[g], oB, 0, 0, 0);
            }
        }
        __syncthreads();
    }
    int b = bh >> 3, hh = bh & 7;
    {
        float inv = 1.f / lacA[0];
        int row = q0 + l15;
        half2t lo = pkrtz(oA[0] * inv, oA[1] * inv);
        half2t hi = pkrtz(oA[2] * inv, oA[3] * inv);
        half4 hv; hv[0] = lo[0]; hv[1] = lo[1]; hv[2] = hi[0]; hv[3] = hi[1];
        *(half4*)(out16 + ((size_t)(b * Nq + row)) * Dq + hh * 16 + l4 * 4) = hv;
    }
    {
        float inv = 1.f / lacB[0];
        int row = q0 + 16 + l15;
        half2t lo = pkrtz(oB[0] * inv, oB[1] * inv);
        half2t hi = pkrtz(oB[2] * inv, oB[3] * inv);
        half4 hv; hv[0] = lo[0]; hv[1] = lo[1]; hv[2] = hi[0]; hv[3] = hi[1];
        *(half4*)(out16 + ((size_t)(b * Nq + row)) * Dq + hh * 16 + l4 * 4) = hv;
    }
}

// ---------------- fused GEMM(Nc=128) + residual(h16) + LayerNorm -> h16 ----------------
__global__ __launch_bounds__(256) void hgemm_ln_kernel(const _Float16* __restrict__ A,
                                                       const _Float16* __restrict__ W,
                                                       const float* __restrict__ bias,
                                                       const float* __restrict__ lnw,
                                                       const float* __restrict__ lnb,
                                                       _Float16* __restrict__ h16,
                                                       int K) {
    int tid = threadIdx.x;
    int lane = tid & 63, w = tid >> 6;
    int l15 = lane & 15, l4 = lane >> 4;
    int m0 = blockIdx.x * 64 + w * 16;
    const _Float16* Ap = A + (size_t)(m0 + l15) * K + l4 * 4;
    const _Float16* Wp = W + (size_t)l15 * K + l4 * 4;
    v4f acc[8] = {};
    for (int ks = 0; ks < K; ks += 16) {
        half4 af = *(const half4*)(Ap + ks);
#pragma unroll
        for (int nt = 0; nt < 8; nt++) {
            half4 wf = *(const half4*)(Wp + (size_t)nt * 16 * K + ks);
            acc[nt] = __builtin_amdgcn_mfma_f32_16x16x16f16(wf, af, acc[nt], 0, 0, 0);
        }
    }
    int m = m0 + l15;
    float x[8][4];
    float psum = 0.f;
#pragma unroll
    for (int nt = 0; nt < 8; nt++) {
        int nb = nt * 16 + l4 * 4;
        float4 bv = *(const float4*)(bias + nb);
        half4 rv = *(const half4*)(h16 + (size_t)m * Dq + nb);
        x[nt][0] = acc[nt][0] + bv.x + (float)rv[0];
        x[nt][1] = acc[nt][1] + bv.y + (float)rv[1];
        x[nt][2] = acc[nt][2] + bv.z + (float)rv[2];
        x[nt][3] = acc[nt][3] + bv.w + (float)rv[3];
        psum += (x[nt][0] + x[nt][1]) + (x[nt][2] + x[nt][3]);
    }
    psum += __shfl_xor(psum, 16);
    psum += __shfl_xor(psum, 32);
    float mean = psum * (1.f / 128.f);
    float vsum = 0.f;
#pragma unroll
    for (int nt = 0; nt < 8; nt++)
#pragma unroll
        for (int r = 0; r < 4; r++) {
            x[nt][r] -= mean;
            vsum += x[nt][r] * x[nt][r];
        }
    vsum += __shfl_xor(vsum, 16);
    vsum += __shfl_xor(vsum, 32);
    float inv = rsqrtf(vsum * (1.f / 128.f) + EPSq);
#pragma unroll
    for (int nt = 0; nt < 8; nt++) {
        int nb = nt * 16 + l4 * 4;
        float4 wv = *(const float4*)(lnw + nb);
        float4 bb = *(const float4*)(lnb + nb);
        float y0 = x[nt][0] * inv * wv.x + bb.x;
        float y1 = x[nt][1] * inv * wv.y + bb.y;
        float y2 = x[nt][2] * inv * wv.z + bb.z;
        float y3 = x[nt][3] * inv * wv.w + bb.w;
        half2t lo = pkrtz(y0, y1);
        half2t hi = pkrtz(y2, y3);
        half4 hv2; hv2[0] = lo[0]; hv2[1] = lo[1]; hv2[2] = hi[0]; hv2[3] = hi[1];
        *(half4*)(h16 + (size_t)m * Dq + nb) = hv2;
    }
}

// ---------------- fused FFN (+ LN). LAST=1: emit per-wave column partial sums for pooling ----------------
template <int LAST>
__global__ __launch_bounds__(256) void ffn_kernel(const _Float16* __restrict__ h16in,
                                                  const _Float16* __restrict__ W1,
                                                  const float* __restrict__ b1,
                                                  const _Float16* __restrict__ W2,
                                                  const float* __restrict__ b2,
                                                  const float* __restrict__ lnw,
                                                  const float* __restrict__ lnb,
                                                  _Float16* __restrict__ h16,
                                                  float* __restrict__ part) {
    int tid = threadIdx.x;
    int lane = tid & 63, w = tid >> 6;
    int l15 = lane & 15, l4 = lane >> 4;
    int m0 = blockIdx.x * 64 + w * 16;
    int m = m0 + l15;
    const _Float16* Ap = h16in + (size_t)m * Dq + l4 * 4;
    half4 afr[8];
#pragma unroll
    for (int t = 0; t < 8; t++) afr[t] = *(const half4*)(Ap + t * 16);
    half4 mid[32];
#pragma unroll
    for (int c = 0; c < 8; c++) {
        v4f acc[4] = {};
#pragma unroll
        for (int t = 0; t < 8; t++) {
#pragma unroll
            for (int nt = 0; nt < 4; nt++) {
                half4 wf = *(const half4*)(W1 + (size_t)(c * 64 + nt * 16 + l15) * 128 + t * 16 + l4 * 4);
                acc[nt] = __builtin_amdgcn_mfma_f32_16x16x16f16(wf, afr[t], acc[nt], 0, 0, 0);
            }
        }
#pragma unroll
        for (int nt = 0; nt < 4; nt++) {
            float4 bv = *(const float4*)(b1 + c * 64 + nt * 16 + l4 * 4);
            float v0 = fmaxf(acc[nt][0] + bv.x, 0.f);
            float v1 = fmaxf(acc[nt][1] + bv.y, 0.f);
            float v2 = fmaxf(acc[nt][2] + bv.z, 0.f);
            float v3 = fmaxf(acc[nt][3] + bv.w, 0.f);
            half2t lo = pkrtz(v0, v1), hi = pkrtz(v2, v3);
            half4 hv; hv[0] = lo[0]; hv[1] = lo[1]; hv[2] = hi[0]; hv[3] = hi[1];
            mid[c * 4 + nt] = hv;
        }
    }
    v4f acc8[8] = {};
#pragma unroll 4
    for (int t = 0; t < 32; t++) {
#pragma unroll
        for (int nt = 0; nt < 8; nt++) {
            half4 wf = *(const half4*)(W2 + (size_t)(nt * 16 + l15) * 512 + t * 16 + l4 * 4);
            acc8[nt] = __builtin_amdgcn_mfma_f32_16x16x16f16(wf, mid[t], acc8[nt], 0, 0, 0);
        }
    }
    float x[8][4];
    float psum = 0.f;
#pragma unroll
    for (int nt = 0; nt < 8; nt++) {
        int nb = nt * 16 + l4 * 4;
        float4 bv = *(const float4*)(b2 + nb);
        x[nt][0] = acc8[nt][0] + bv.x + (float)afr[nt][0];
        x[nt][1] = acc8[nt][1] + bv.y + (float)afr[nt][1];
        x[nt][2] = acc8[nt][2] + bv.z + (float)afr[nt][2];
        x[nt][3] = acc8[nt][3] + bv.w + (float)afr[nt][3];
        psum += (x[nt][0] + x[nt][1]) + (x[nt][2] + x[nt][3]);
    }
    psum += __shfl_xor(psum, 16);
    psum += __shfl_xor(psum, 32);
    float mean = psum * (1.f / 128.f);
    float vsum = 0.f;
#pragma unroll
    for (int nt = 0; nt < 8; nt++)
#pragma unroll
        for (int r = 0; r < 4; r++) {
            x[nt][r] -= mean;
            vsum += x[nt][r] * x[nt][r];
        }
    vsum += __shfl_xor(vsum, 16);
    vsum += __shfl_xor(vsum, 32);
    float inv = rsqrtf(vsum * (1.f / 128.f) + EPSq);
#pragma unroll
    for (int nt = 0; nt < 8; nt++) {
        int nb = nt * 16 + l4 * 4;
        float4 wv = *(const float4*)(lnw + nb);
        float4 bb = *(const float4*)(lnb + nb);
        x[nt][0] = x[nt][0] * inv * wv.x + bb.x;
        x[nt][1] = x[nt][1] * inv * wv.y + bb.y;
        x[nt][2] = x[nt][2] * inv * wv.z + bb.z;
        x[nt][3] = x[nt][3] * inv * wv.w + bb.w;
        if (!LAST) {
            half2t lo = pkrtz(x[nt][0], x[nt][1]);
            half2t hi = pkrtz(x[nt][2], x[nt][3]);
            half4 hv2; hv2[0] = lo[0]; hv2[1] = lo[1]; hv2[2] = hi[0]; hv2[3] = hi[1];
            *(half4*)(h16 + (size_t)m * Dq + nb) = hv2;
        }
    }
    if (LAST) {
#pragma unroll
        for (int nt = 0; nt < 8; nt++)
#pragma unroll
            for (int r = 0; r < 4; r++) {
                float v = x[nt][r];
                v += __shfl_xor(v, 1);
                v += __shfl_xor(v, 2);
                v += __shfl_xor(v, 4);
                v += __shfl_xor(v, 8);
                x[nt][r] = v;
            }
        if (l15 == 0) {
            float* pp = part + ((size_t)blockIdx.x * 4 + w) * Dq;
#pragma unroll
            for (int nt = 0; nt < 8; nt++)
#pragma unroll
                for (int r = 0; r < 4; r++)
                    pp[nt * 16 + l4 * 4 + r] = x[nt][r];
        }
    }
}

// ---------------- head: pooled = mean over N via 256 wave-partials; MLP + sigmoid ----------------
__global__ __launch_bounds__(512) void head_kernel(const float* __restrict__ part,
                                                   const float* __restrict__ fc1_w, const float* __restrict__ fc1_b,
                                                   const float* __restrict__ fc2_w, const float* __restrict__ fc2_b,
                                                   float* __restrict__ out) {
    __shared__ float psh[Dq];
    __shared__ float red[512];
    int b = blockIdx.x, f = threadIdx.x;
    if (f < Dq) {
        float s = 0.f;
        for (int c = 0; c < 256; c++) s += part[((size_t)b * 256 + c) * Dq + f];
        psh[f] = s * (1.f / 4096.f);
    }
    __syncthreads();
    const float* wr = fc1_w + (size_t)f * Dq;
    float s = fc1_b[f];
    for (int d = 0; d < Dq; d++) s += psh[d] * wr[d];
    red[f] = fmaxf(s, 0.f) * fc2_w[f];
    __syncthreads();
    for (int st = 256; st > 0; st >>= 1) {
        if (f < st) red[f] += red[f + st];
        __syncthreads();
    }
    if (f == 0) out[b] = 1.f / (1.f + __expf(-(red[0] + fc2_b[0])));
}

extern "C" void kernel_launch(void* const* d_in, const int* in_sizes, int n_in,
                              void* d_out, int out_size, void* d_ws, size_t ws_size,
                              hipStream_t stream) {
    const float* x        = (const float*)d_in[0];
    const float* xyz_w    = (const float*)d_in[1];
    const float* xyz_b    = (const float*)d_in[2];
    const float* ohe_w    = (const float*)d_in[3];
    const float* ohe_b    = (const float*)d_in[4];
    const float* in_proj_w  = (const float*)d_in[5];
    const float* in_proj_b  = (const float*)d_in[6];
    const float* out_proj_w = (const float*)d_in[7];
    const float* out_proj_b = (const float*)d_in[8];
    const float* ln1_w    = (const float*)d_in[9];
    const float* ln1_b    = (const float*)d_in[10];
    const float* lin1_w   = (const float*)d_in[11];
    const float* lin1_b   = (const float*)d_in[12];
    const float* lin2_w   = (const float*)d_in[13];
    const float* lin2_b   = (const float*)d_in[14];
    const float* ln2_w    = (const float*)d_in[15];
    const float* ln2_b    = (const float*)d_in[16];
    const float* fc1_w    = (const float*)d_in[17];
    const float* fc1_b    = (const float*)d_in[18];
    const float* fc2_w    = (const float*)d_in[19];
    const float* fc2_b    = (const float*)d_in[20];
    float* outp = (float*)d_out;

    char* ws = (char*)d_ws;
    size_t off = 0;
    auto alloc = [&](size_t bytes) { void* p = ws + off; off += (bytes + 255) & ~255ULL; return p; };
    _Float16*  feat16 = (_Float16*)alloc((size_t)Bq * Nq * Dq * 2);
    _Float16*  h16    = (_Float16*)alloc((size_t)Bq * Nq * Dq * 2);
    _Float16*  abuf16 = (_Float16*)alloc((size_t)Bq * Nq * Dq * 2);
    _Float16*  pkb    = (_Float16*)alloc(3ull * 64 * Nq * 16 * 2);
    _Float16*  wb     = (_Float16*)alloc(393216ull * 2);
    int*       idx    = (int*)alloc((size_t)Bq * Nq * KNNq * 4);
    float*     part   = (float*)alloc(2048ull * Dq * 4);
    if (off > ws_size) return;

    const _Float16* wip16 = wb;
    const _Float16* wop16 = wb + 98304;
    const _Float16* wl116 = wb + 131072;
    const _Float16* wl216 = wb + 262144;

    int M = Bq * Nq;

    prep_kernel<<<16384 + 1536, 256, 0, stream>>>(x, xyz_w, xyz_b, ohe_w, ohe_b, feat16,
                                                  in_proj_w, out_proj_w, lin1_w, lin2_w, wb);
    knn_kernel<<<dim3(Nq / 64, Bq), 512, 0, stream>>>(x, idx);
    knn_attn_kernel<<<M / 4, 256, 0, stream>>>(feat16, idx, h16);

    for (int l = 0; l < Lq; l++) {
        hgemm_kernel<2><<<dim3(384 / 64, M / 64), 256, 0, stream>>>(
            h16, wip16 + (size_t)l * 384 * 128, in_proj_b + l * 384, pkb, M, 384, 128);
        flash16_kernel<<<dim3(Nq / 128, Bq * Hq), 256, 0, stream>>>(pkb, abuf16);
        hgemm_ln_kernel<<<M / 64, 256, 0, stream>>>(
            abuf16, wop16 + (size_t)l * 128 * 128, out_proj_b + l * 128,
            ln1_w + l * 128, ln1_b + l * 128, h16, 128);
        if (l == 0) {
            ffn_kernel<0><<<M / 64, 256, 0, stream>>>(
                h16, wl116, lin1_b, wl216, lin2_b, ln2_w, ln2_b, h16, part);
        } else {
            ffn_kernel<1><<<M / 64, 256, 0, stream>>>(
                h16, wl116 + (size_t)l * 512 * 128, lin1_b + l * 512,
                wl216 + (size_t)l * 128 * 512, lin2_b + l * 128,
                ln2_w + l * 128, ln2_b + l * 128, h16, part);
        }
    }

    head_kernel<<<Bq, 512, 0, stream>>>(part, fc1_w, fc1_b, fc2_w, fc2_b, outp);
}

// Round 9
// 1010.208 us; speedup vs baseline: 1.2498x; 1.2047x over previous
//
#include <hip/hip_runtime.h>

#define Bq 8
#define Nq 4096
#define Dq 128
#define Hq 8
#define FFq 512
#define KNNq 16
#define Lq 2
#define DHq 16
#define EPSq 1e-5f

typedef _Float16 half4 __attribute__((ext_vector_type(4)));
typedef _Float16 half2t __attribute__((ext_vector_type(2)));
typedef float v4f __attribute__((ext_vector_type(4)));

static __device__ __forceinline__ half2t pkrtz(float a, float b) {
    return __builtin_bit_cast(half2t, __builtin_amdgcn_cvt_pkrtz(a, b));
}

// ---------------- fused prep: feat (f16) + weight fp32->f16 conversion ----------------
__global__ __launch_bounds__(256) void prep_kernel(const float* __restrict__ x,
                                                   const float* __restrict__ xyz_w,
                                                   const float* __restrict__ xyz_b,
                                                   const float* __restrict__ ohe_w,
                                                   const float* __restrict__ ohe_b,
                                                   _Float16* __restrict__ feat16,
                                                   const float* __restrict__ ipw,
                                                   const float* __restrict__ opw,
                                                   const float* __restrict__ l1w,
                                                   const float* __restrict__ l2w,
                                                   _Float16* __restrict__ wb) {
    int bid = blockIdx.x;
    if (bid < 16384) {
        int i = bid * 256 + threadIdx.x;
        int d = i & 127;
        int t = i >> 7;
        const float* xr = x + (size_t)t * 8;
        float s = xyz_b[d] + ohe_b[d];
        s += xr[0] * xyz_w[d * 3 + 0] + xr[1] * xyz_w[d * 3 + 1] + xr[2] * xyz_w[d * 3 + 2];
        s += xr[3] * ohe_w[d * 5 + 0] + xr[4] * ohe_w[d * 5 + 1] + xr[5] * ohe_w[d * 5 + 2]
           + xr[6] * ohe_w[d * 5 + 3] + xr[7] * ohe_w[d * 5 + 4];
        feat16[i] = (_Float16)s;
    } else {
        int i = (bid - 16384) * 256 + threadIdx.x;
        float v;
        if (i < 98304) v = ipw[i];
        else if (i < 131072) v = opw[i - 98304];
        else if (i < 262144) v = l1w[i - 131072];
        else v = l2w[i - 262144];
        wb[i] = (_Float16)v;
    }
}

// ---------------- KNN top-16 v9: batched bitonic selection, no per-candidate self-mask.
// Self point (d2=0 -> key=n) is always the global minimum of its partition; epilogue picks
// 17 and discards the first — exactly reference's idx[...,1:] semantics. ----------------
__global__ __launch_bounds__(512) void knn_kernel(const float* __restrict__ x, int* __restrict__ idx) {
    __shared__ __attribute__((aligned(16))) float sx[Nq];  // 16 KB
    __shared__ __attribute__((aligned(16))) float sy[Nq];  // 16 KB
    __shared__ __attribute__((aligned(16))) float sz[Nq];  // 16 KB -> 48 KB
    unsigned int (*md)[17] = (unsigned int (*)[17])sx;     // 512*17*4 = 34 KB, aliased (dead after scan)
    int b = blockIdx.y;
    int tid = threadIdx.x;
    for (int p = tid; p < Nq; p += 512) {
        const float* xr = x + ((size_t)b * Nq + p) * 8;
        sx[p] = xr[0]; sy[p] = xr[1]; sz[p] = xr[2];
    }
    __syncthreads();
    int qi = tid >> 3;   // 0..63 local query
    int part = tid & 7;
    int n = blockIdx.x * 64 + qi;
    float qx = sx[n], qy = sy[n], qz = sz[n];
    unsigned int top[16];
#pragma unroll
    for (int i = 0; i < 16; i++) top[i] = 0xFFFFFFFFu;
    int j0 = part * 512;
    int rot = part; // bank offset: partitions land on distinct banks, same-part lanes broadcast
    for (int bb = 0; bb < 32; bb++) {
        unsigned int c[16];
#pragma unroll
        for (int u = 0; u < 16; u++) {
            int j = j0 + ((bb * 16 + rot + u) & 511);
            float px = sx[j], py = sy[j], pz = sz[j];
            float dx = qx - px, dy = qy - py, dz = qz - pz;
            float d2 = fmaf(dx, dx, fmaf(dy, dy, dz * dz));
            c[u] = (__float_as_uint(d2) & 0xFFFFF000u) | (unsigned int)j;  // self -> key = n (min)
        }
        // bitonic sort c[16] ascending (80 compare-exchanges, 8-way ILP per substage)
#pragma unroll
        for (int kk = 2; kk <= 16; kk <<= 1) {
#pragma unroll
            for (int jj = 16 >> 1; jj > 0; jj >>= 1) {
                if (jj < kk) {
#pragma unroll
                    for (int i = 0; i < 16; i++) {
                        int l = i ^ jj;
                        if (l > i) {
                            unsigned int a0 = c[i], b0 = c[l];
                            unsigned int mn = a0 < b0 ? a0 : b0;
                            unsigned int mx = a0 < b0 ? b0 : a0;
                            bool up = ((i & kk) == 0);
                            c[i] = up ? mn : mx;
                            c[l] = up ? mx : mn;
                        }
                    }
                }
            }
        }
        // merge: keep smallest 16 of top ∪ c (bitonic lower half)
#pragma unroll
        for (int i = 0; i < 16; i++) {
            unsigned int a0 = top[i], b0 = c[15 - i];
            top[i] = a0 < b0 ? a0 : b0;
        }
        // half-cleaner cascade: sort the bitonic top[16] ascending
#pragma unroll
        for (int d = 8; d >= 1; d >>= 1) {
#pragma unroll
            for (int i = 0; i < 16; i++) {
                if ((i & d) == 0) {
                    int l = i | d;
                    unsigned int a0 = top[i], b0 = top[l];
                    top[i] = a0 < b0 ? a0 : b0;
                    top[l] = a0 < b0 ? b0 : a0;
                }
            }
        }
    }
    __syncthreads(); // all waves done scanning before md overwrites the scan buffer
#pragma unroll
    for (int i = 0; i < 16; i++) md[tid][i] = top[i];
    md[tid][16] = 0xFFFFFFFFu;  // sentinel: partition exhausted
    __syncthreads();
    if (part == 0) {
        unsigned long long pall = 0;  // 5-bit pick counters (17 picks can exceed 4 bits)
        int* op = idx + ((size_t)b * Nq + n) * KNNq;
        int base_row = qi * 8;
#pragma unroll
        for (int s = 0; s < KNNq + 1; s++) {
            unsigned int best = 0xFFFFFFFFu; int bp = 0;
#pragma unroll
            for (int p2 = 0; p2 < 8; p2++) {
                unsigned int ptr = (unsigned int)((pall >> (p2 * 5)) & 31u);
                unsigned int v = md[base_row + p2][ptr];
                if (v < best) { best = v; bp = p2; }
            }
            if (s > 0) op[s - 1] = (int)(best & 4095u);  // drop pick 0 = self
            pall += (1ull << (bp * 5));
        }
    }
}

// ---------------- KNN attention: f16 gathers, f32 math, emits h16 only ----------------
__global__ __launch_bounds__(256, 4) void knn_attn_kernel(const _Float16* __restrict__ feat16,
                                                          const int* __restrict__ idx,
                                                          _Float16* __restrict__ h16) {
    int wave = threadIdx.x >> 6;
    int lane = threadIdx.x & 63;
    int token = blockIdx.x * 4 + wave;
    int b = token >> 12;
    half2t fh = ((const half2t*)(feat16 + (size_t)token * Dq))[lane];
    float2 f = make_float2((float)fh[0], (float)fh[1]);
    const int* ip = idx + (size_t)token * KNNq;
    int jj[KNNq];
#pragma unroll
    for (int k = 0; k < KNNq; k++) jj[k] = ip[k];
    float2 g[KNNq];
#pragma unroll
    for (int k = 0; k < KNNq; k++) {
        half2t gh = ((const half2t*)(feat16 + (((size_t)b << 12) + jj[k]) * Dq))[lane];
        g[k] = make_float2((float)gh[0], (float)gh[1]);
    }
    float sc[KNNq];
#pragma unroll
    for (int k = 0; k < KNNq; k++) {
        float p = f.x * g[k].x + f.y * g[k].y;
#pragma unroll
        for (int m = 1; m < 64; m <<= 1) p += __shfl_xor(p, m);
        sc[k] = p * 0.088388347648318447f; // 1/sqrt(128)
    }
    float mx = sc[0];
#pragma unroll
    for (int k = 1; k < KNNq; k++) mx = fmaxf(mx, sc[k]);
    float sum = 0.f;
#pragma unroll
    for (int k = 0; k < KNNq; k++) { sc[k] = __expf(sc[k] - mx); sum += sc[k]; }
    float inv = 1.f / sum;
    float o0 = 0.f, o1 = 0.f;
#pragma unroll
    for (int k = 0; k < KNNq; k++) { o0 += sc[k] * g[k].x; o1 += sc[k] * g[k].y; }
    ((half2t*)(h16 + (size_t)token * Dq))[lane] = pkrtz(o0 * inv, o1 * inv);
}

// ---------------- f16 MFMA GEMM, LDS-free ----------------
// MODE 2: qkv pack — Q (pre-scaled by 0.25*log2e) and K to pk[sel][bh][n][16],
// V TRANSPOSED to slot2 as Vt[bh][d][n].
template <int MODE>
__global__ __launch_bounds__(256) void hgemm_kernel(const _Float16* __restrict__ A,
                                                    const _Float16* __restrict__ W,
                                                    const float* __restrict__ bias,
                                                    void* __restrict__ Cout,
                                                    int M, int Nc, int K) {
    int tid = threadIdx.x;
    int lane = tid & 63, w = tid >> 6;
    int l15 = lane & 15, l4 = lane >> 4;
    int m0 = blockIdx.y * 64 + w * 16;
    int n0 = blockIdx.x * 64;
    const _Float16* Ap = A + (size_t)(m0 + l15) * K + l4 * 4;
    const _Float16* Wp = W + (size_t)(n0 + l15) * K + l4 * 4;
    v4f acc[4] = {{0.f, 0.f, 0.f, 0.f}, {0.f, 0.f, 0.f, 0.f}, {0.f, 0.f, 0.f, 0.f}, {0.f, 0.f, 0.f, 0.f}};
    for (int ks = 0; ks < K; ks += 16) {
        half4 af = *(const half4*)(Ap + ks);
#pragma unroll
        for (int nt = 0; nt < 4; nt++) {
            half4 wf = *(const half4*)(Wp + (size_t)nt * 16 * K + ks);
            acc[nt] = __builtin_amdgcn_mfma_f32_16x16x16f16(wf, af, acc[nt], 0, 0, 0);
        }
    }
    int m = m0 + l15;
#pragma unroll
    for (int nt = 0; nt < 4; nt++) {
        int nb = n0 + nt * 16 + l4 * 4;
        float4 bv = *(const float4*)(bias + nb);
        float v0 = acc[nt][0] + bv.x, v1 = acc[nt][1] + bv.y;
        float v2 = acc[nt][2] + bv.z, v3 = acc[nt][3] + bv.w;
        int n_base = n0 + nt * 16;
        int sel = n_base >> 7;
        if (MODE == 2 && sel == 0) {
            v0 *= 0.36067376f; v1 *= 0.36067376f; v2 *= 0.36067376f; v3 *= 0.36067376f;
        }
        half2t lo = pkrtz(v0, v1);
        half2t hi = pkrtz(v2, v3);
        half4 hv; hv[0] = lo[0]; hv[1] = lo[1]; hv[2] = hi[0]; hv[3] = hi[1];
        if (sel < 2) {
            int hh = (n_base >> 4) & 7;
            size_t base = (size_t)sel * (64ull * Nq * 16)
                        + ((size_t)((m >> 12) * 8 + hh)) * (Nq * 16)
                        + (size_t)(m & 4095) * 16 + l4 * 4;
            *(half4*)((_Float16*)Cout + base) = hv;
        } else {
            int hh = (n_base >> 4) & 7;
            size_t vb = 2ull * 64 * Nq * 16
                      + ((size_t)((m >> 12) * 8 + hh)) * (16 * Nq)
                      + (size_t)(m & 4095);
            _Float16* vp = (_Float16*)Cout + vb + (size_t)(l4 * 4) * Nq;
            vp[0 * Nq] = hv[0]; vp[1 * Nq] = hv[1]; vp[2 * Nq] = hv[2]; vp[3 * Nq] = hv[3];
        }
    }
}

// ---------------- flash v12 (measured best, 197 us): 2 q-tiles per wave, lsum via ones-MFMA,
// top-staged dbuf, v_exp_f32. Verbatim revert — all schedule edits measured worse. ----------------
__global__ __launch_bounds__(256) void flash12_kernel(const _Float16* __restrict__ pk,
                                                      _Float16* __restrict__ out16) {
    __shared__ _Float16 Ks[2][64 * 20];
    __shared__ _Float16 Vs[2][16 * 66];
    int tid = threadIdx.x;
    int lane = tid & 63, w = tid >> 6;
    int bh = blockIdx.y;
    const _Float16* Qb = pk + (size_t)bh * (Nq * 16);
    const _Float16* Kb = pk + (size_t)(64 + bh) * (Nq * 16);
    const _Float16* Vt = pk + 2ull * 64 * Nq * 16 + (size_t)bh * (16 * Nq);
    int q0 = blockIdx.x * 128 + w * 32;
    int l15 = lane & 15, l4 = lane >> 4;

    half4 qfA = *(const half4*)(Qb + (size_t)(q0 + l15) * 16 + l4 * 4);
    half4 qfB = *(const half4*)(Qb + (size_t)(q0 + 16 + l15) * 16 + l4 * 4);

    int sr = tid >> 2, sc = tid & 3;
    int vd = tid >> 4, vj = (tid & 15) * 4;
    const _Float16* Kg = Kb + (size_t)sr * 16 + sc * 4;
    const _Float16* Vg = Vt + (size_t)vd * Nq + vj;

    *(half4*)(Ks[0] + sr * 20 + sc * 4) = *(const half4*)(Kg);
    *(half4*)(Vs[0] + vd * 66 + vj) = *(const half4*)(Vg);
    __syncthreads();

    v4f oA = {0.f, 0.f, 0.f, 0.f}, oB = {0.f, 0.f, 0.f, 0.f};
    v4f lacA = {0.f, 0.f, 0.f, 0.f}, lacB = {0.f, 0.f, 0.f, 0.f};
    half4 ones;
    ones[0] = ones[1] = ones[2] = ones[3] = (_Float16)1.0f;

    for (int kt = 0; kt < Nq / 64; kt++) {
        int cur = kt & 1, nxt = cur ^ 1;
        if (kt < Nq / 64 - 1) {
            *(half4*)(Ks[nxt] + sr * 20 + sc * 4) = *(const half4*)(Kg + (size_t)(kt + 1) * 64 * 16);
            *(half4*)(Vs[nxt] + vd * 66 + vj) = *(const half4*)(Vg + (kt + 1) * 64);
        }
        half4 kf[4];
#pragma unroll
        for (int g = 0; g < 4; g++)
            kf[g] = *(const half4*)(Ks[cur] + (g * 16 + l15) * 20 + l4 * 4);
        v4f SA[4], SB[4];
#pragma unroll
        for (int g = 0; g < 4; g++) {
            SA[g] = __builtin_amdgcn_mfma_f32_16x16x16f16(kf[g], qfA, (v4f){0.f, 0.f, 0.f, 0.f}, 0, 0, 0);
            SB[g] = __builtin_amdgcn_mfma_f32_16x16x16f16(kf[g], qfB, (v4f){0.f, 0.f, 0.f, 0.f}, 0, 0, 0);
        }
        half4 PA[4], PB[4];
#pragma unroll
        for (int g = 0; g < 4; g++) {
            float a0 = __builtin_amdgcn_exp2f(SA[g][0]);
            float a1 = __builtin_amdgcn_exp2f(SA[g][1]);
            float a2 = __builtin_amdgcn_exp2f(SA[g][2]);
            float a3 = __builtin_amdgcn_exp2f(SA[g][3]);
            half2t alo = pkrtz(a0, a1);
            half2t ahi = pkrtz(a2, a3);
            PA[g][0] = alo[0]; PA[g][1] = alo[1]; PA[g][2] = ahi[0]; PA[g][3] = ahi[1];
            float b0 = __builtin_amdgcn_exp2f(SB[g][0]);
            float b1 = __builtin_amdgcn_exp2f(SB[g][1]);
            float b2 = __builtin_amdgcn_exp2f(SB[g][2]);
            float b3 = __builtin_amdgcn_exp2f(SB[g][3]);
            half2t blo = pkrtz(b0, b1);
            half2t bhi = pkrtz(b2, b3);
            PB[g][0] = blo[0]; PB[g][1] = blo[1]; PB[g][2] = bhi[0]; PB[g][3] = bhi[1];
        }
#pragma unroll
        for (int g = 0; g < 4; g++) {
            half4 vf = *(const half4*)(Vs[cur] + l15 * 66 + g * 16 + l4 * 4);
            lacA = __builtin_amdgcn_mfma_f32_16x16x16f16(ones, PA[g], lacA, 0, 0, 0);
            oA = __builtin_amdgcn_mfma_f32_16x16x16f16(vf, PA[g], oA, 0, 0, 0);
            lacB = __builtin_amdgcn_mfma_f32_16x16x16f16(ones, PB[g], lacB, 0, 0, 0);
            oB = __builtin_amdgcn_mfma_f32_16x16x16f16(vf, PB[g], oB, 0, 0, 0);
        }
        __syncthreads();
    }
    int b = bh >> 3, hh = bh & 7;
    {
        float inv = 1.f / lacA[0];
        int row = q0 + l15;
        half2t lo = pkrtz(oA[0] * inv, oA[1] * inv);
        half2t hi = pkrtz(oA[2] * inv, oA[3] * inv);
        half4 hv; hv[0] = lo[0]; hv[1] = lo[1]; hv[2] = hi[0]; hv[3] = hi[1];
        *(half4*)(out16 + ((size_t)(b * Nq + row)) * Dq + hh * 16 + l4 * 4) = hv;
    }
    {
        float inv = 1.f / lacB[0];
        int row = q0 + 16 + l15;
        half2t lo = pkrtz(oB[0] * inv, oB[1] * inv);
        half2t hi = pkrtz(oB[2] * inv, oB[3] * inv);
        half4 hv; hv[0] = lo[0]; hv[1] = lo[1]; hv[2] = hi[0]; hv[3] = hi[1];
        *(half4*)(out16 + ((size_t)(b * Nq + row)) * Dq + hh * 16 + l4 * 4) = hv;
    }
}

// ---------------- fused out_proj GEMM + residual + LN1 + FFN + residual + LN2 ----------------
// Block i of old hgemm_ln and old ffn both touch exactly rows [64i,64i+64) -> zero-hazard fusion.
// Kills 2 dispatches/layer, the 8MB post-LN1 h16 write + 8MB reload (afr stays in registers).
template <int LAST>
__global__ __launch_bounds__(256) void oln_ffn_kernel(const _Float16* __restrict__ A,
                                                      const _Float16* __restrict__ Wo,
                                                      const float* __restrict__ bo,
                                                      const float* __restrict__ ln1w,
                                                      const float* __restrict__ ln1b,
                                                      const _Float16* __restrict__ W1,
                                                      const float* __restrict__ b1,
                                                      const _Float16* __restrict__ W2,
                                                      const float* __restrict__ b2,
                                                      const float* __restrict__ ln2w,
                                                      const float* __restrict__ ln2b,
                                                      _Float16* __restrict__ h16,
                                                      float* __restrict__ part) {
    int tid = threadIdx.x;
    int lane = tid & 63, w = tid >> 6;
    int l15 = lane & 15, l4 = lane >> 4;
    int m0 = blockIdx.x * 64 + w * 16;
    int m = m0 + l15;

    // ---- part 1: out_proj GEMM (K=128) + residual + LN1 -> afr (registers) ----
    const _Float16* Ap = A + (size_t)m * 128 + l4 * 4;
    const _Float16* Wp = Wo + (size_t)l15 * 128 + l4 * 4;
    v4f acc[8] = {};
    for (int ks = 0; ks < 128; ks += 16) {
        half4 af = *(const half4*)(Ap + ks);
#pragma unroll
        for (int nt = 0; nt < 8; nt++) {
            half4 wf = *(const half4*)(Wp + (size_t)nt * 16 * 128 + ks);
            acc[nt] = __builtin_amdgcn_mfma_f32_16x16x16f16(wf, af, acc[nt], 0, 0, 0);
        }
    }
    float x[8][4];
    float psum = 0.f;
#pragma unroll
    for (int nt = 0; nt < 8; nt++) {
        int nb = nt * 16 + l4 * 4;
        float4 bv = *(const float4*)(bo + nb);
        half4 rv = *(const half4*)(h16 + (size_t)m * Dq + nb);
        x[nt][0] = acc[nt][0] + bv.x + (float)rv[0];
        x[nt][1] = acc[nt][1] + bv.y + (float)rv[1];
        x[nt][2] = acc[nt][2] + bv.z + (float)rv[2];
        x[nt][3] = acc[nt][3] + bv.w + (float)rv[3];
        psum += (x[nt][0] + x[nt][1]) + (x[nt][2] + x[nt][3]);
    }
    psum += __shfl_xor(psum, 16);
    psum += __shfl_xor(psum, 32);
    float mean = psum * (1.f / 128.f);
    float vsum = 0.f;
#pragma unroll
    for (int nt = 0; nt < 8; nt++)
#pragma unroll
        for (int r = 0; r < 4; r++) {
            x[nt][r] -= mean;
            vsum += x[nt][r] * x[nt][r];
        }
    vsum += __shfl_xor(vsum, 16);
    vsum += __shfl_xor(vsum, 32);
    float inv1 = rsqrtf(vsum * (1.f / 128.f) + EPSq);
    half4 afr[8];
#pragma unroll
    for (int nt = 0; nt < 8; nt++) {
        int nb = nt * 16 + l4 * 4;
        float4 wv = *(const float4*)(ln1w + nb);
        float4 bb = *(const float4*)(ln1b + nb);
        float y0 = x[nt][0] * inv1 * wv.x + bb.x;
        float y1 = x[nt][1] * inv1 * wv.y + bb.y;
        float y2 = x[nt][2] * inv1 * wv.z + bb.z;
        float y3 = x[nt][3] * inv1 * wv.w + bb.w;
        half2t lo = pkrtz(y0, y1);
        half2t hi = pkrtz(y2, y3);
        afr[nt][0] = lo[0]; afr[nt][1] = lo[1]; afr[nt][2] = hi[0]; afr[nt][3] = hi[1];
    }

    // ---- part 2: FFN (W1/relu/W2) + residual(afr) + LN2 ----
    half4 mid[32];
#pragma unroll
    for (int c = 0; c < 8; c++) {
        v4f accm[4] = {};
#pragma unroll
        for (int t = 0; t < 8; t++) {
#pragma unroll
            for (int nt = 0; nt < 4; nt++) {
                half4 wf = *(const half4*)(W1 + (size_t)(c * 64 + nt * 16 + l15) * 128 + t * 16 + l4 * 4);
                accm[nt] = __builtin_amdgcn_mfma_f32_16x16x16f16(wf, afr[t], accm[nt], 0, 0, 0);
            }
        }
#pragma unroll
        for (int nt = 0; nt < 4; nt++) {
            float4 bv = *(const float4*)(b1 + c * 64 + nt * 16 + l4 * 4);
            float v0 = fmaxf(accm[nt][0] + bv.x, 0.f);
            float v1 = fmaxf(accm[nt][1] + bv.y, 0.f);
            float v2 = fmaxf(accm[nt][2] + bv.z, 0.f);
            float v3 = fmaxf(accm[nt][3] + bv.w, 0.f);
            half2t lo = pkrtz(v0, v1), hi = pkrtz(v2, v3);
            half4 hv; hv[0] = lo[0]; hv[1] = lo[1]; hv[2] = hi[0]; hv[3] = hi[1];
            mid[c * 4 + nt] = hv;
        }
    }
    v4f acc8[8] = {};
#pragma unroll 4
    for (int t = 0; t < 32; t++) {
#pragma unroll
        for (int nt = 0; nt < 8; nt++) {
            half4 wf = *(const half4*)(W2 + (size_t)(nt * 16 + l15) * 512 + t * 16 + l4 * 4);
            acc8[nt] = __builtin_amdgcn_mfma_f32_16x16x16f16(wf, mid[t], acc8[nt], 0, 0, 0);
        }
    }
    float x2[8][4];
    float psum2 = 0.f;
#pragma unroll
    for (int nt = 0; nt < 8; nt++) {
        int nb = nt * 16 + l4 * 4;
        float4 bv = *(const float4*)(b2 + nb);
        x2[nt][0] = acc8[nt][0] + bv.x + (float)afr[nt][0];
        x2[nt][1] = acc8[nt][1] + bv.y + (float)afr[nt][1];
        x2[nt][2] = acc8[nt][2] + bv.z + (float)afr[nt][2];
        x2[nt][3] = acc8[nt][3] + bv.w + (float)afr[nt][3];
        psum2 += (x2[nt][0] + x2[nt][1]) + (x2[nt][2] + x2[nt][3]);
    }
    psum2 += __shfl_xor(psum2, 16);
    psum2 += __shfl_xor(psum2, 32);
    float mean2 = psum2 * (1.f / 128.f);
    float vsum2 = 0.f;
#pragma unroll
    for (int nt = 0; nt < 8; nt++)
#pragma unroll
        for (int r = 0; r < 4; r++) {
            x2[nt][r] -= mean2;
            vsum2 += x2[nt][r] * x2[nt][r];
        }
    vsum2 += __shfl_xor(vsum2, 16);
    vsum2 += __shfl_xor(vsum2, 32);
    float inv2 = rsqrtf(vsum2 * (1.f / 128.f) + EPSq);
#pragma unroll
    for (int nt = 0; nt < 8; nt++) {
        int nb = nt * 16 + l4 * 4;
        float4 wv = *(const float4*)(ln2w + nb);
        float4 bb = *(const float4*)(ln2b + nb);
        x2[nt][0] = x2[nt][0] * inv2 * wv.x + bb.x;
        x2[nt][1] = x2[nt][1] * inv2 * wv.y + bb.y;
        x2[nt][2] = x2[nt][2] * inv2 * wv.z + bb.z;
        x2[nt][3] = x2[nt][3] * inv2 * wv.w + bb.w;
        if (!LAST) {
            half2t lo = pkrtz(x2[nt][0], x2[nt][1]);
            half2t hi = pkrtz(x2[nt][2], x2[nt][3]);
            half4 hv2; hv2[0] = lo[0]; hv2[1] = lo[1]; hv2[2] = hi[0]; hv2[3] = hi[1];
            *(half4*)(h16 + (size_t)m * Dq + nb) = hv2;
        }
    }
    if (LAST) {
#pragma unroll
        for (int nt = 0; nt < 8; nt++)
#pragma unroll
            for (int r = 0; r < 4; r++) {
                float v = x2[nt][r];
                v += __shfl_xor(v, 1);
                v += __shfl_xor(v, 2);
                v += __shfl_xor(v, 4);
                v += __shfl_xor(v, 8);
                x2[nt][r] = v;
            }
        if (l15 == 0) {
            float* pp = part + ((size_t)blockIdx.x * 4 + w) * Dq;
#pragma unroll
            for (int nt = 0; nt < 8; nt++)
#pragma unroll
                for (int r = 0; r < 4; r++)
                    pp[nt * 16 + l4 * 4 + r] = x2[nt][r];
        }
    }
}

// ---------------- head: pooled = mean over N via 256 wave-partials; MLP + sigmoid ----------------
__global__ __launch_bounds__(512) void head_kernel(const float* __restrict__ part,
                                                   const float* __restrict__ fc1_w, const float* __restrict__ fc1_b,
                                                   const float* __restrict__ fc2_w, const float* __restrict__ fc2_b,
                                                   float* __restrict__ out) {
    __shared__ float psh[Dq];
    __shared__ float red[512];
    int b = blockIdx.x, f = threadIdx.x;
    if (f < Dq) {
        float s = 0.f;
        for (int c = 0; c < 256; c++) s += part[((size_t)b * 256 + c) * Dq + f];
        psh[f] = s * (1.f / 4096.f);
    }
    __syncthreads();
    const float* wr = fc1_w + (size_t)f * Dq;
    float s = fc1_b[f];
    for (int d = 0; d < Dq; d++) s += psh[d] * wr[d];
    red[f] = fmaxf(s, 0.f) * fc2_w[f];
    __syncthreads();
    for (int st = 256; st > 0; st >>= 1) {
        if (f < st) red[f] += red[f + st];
        __syncthreads();
    }
    if (f == 0) out[b] = 1.f / (1.f + __expf(-(red[0] + fc2_b[0])));
}

extern "C" void kernel_launch(void* const* d_in, const int* in_sizes, int n_in,
                              void* d_out, int out_size, void* d_ws, size_t ws_size,
                              hipStream_t stream) {
    const float* x        = (const float*)d_in[0];
    const float* xyz_w    = (const float*)d_in[1];
    const float* xyz_b    = (const float*)d_in[2];
    const float* ohe_w    = (const float*)d_in[3];
    const float* ohe_b    = (const float*)d_in[4];
    const float* in_proj_w  = (const float*)d_in[5];
    const float* in_proj_b  = (const float*)d_in[6];
    const float* out_proj_w = (const float*)d_in[7];
    const float* out_proj_b = (const float*)d_in[8];
    const float* ln1_w    = (const float*)d_in[9];
    const float* ln1_b    = (const float*)d_in[10];
    const float* lin1_w   = (const float*)d_in[11];
    const float* lin1_b   = (const float*)d_in[12];
    const float* lin2_w   = (const float*)d_in[13];
    const float* lin2_b   = (const float*)d_in[14];
    const float* ln2_w    = (const float*)d_in[15];
    const float* ln2_b    = (const float*)d_in[16];
    const float* fc1_w    = (const float*)d_in[17];
    const float* fc1_b    = (const float*)d_in[18];
    const float* fc2_w    = (const float*)d_in[19];
    const float* fc2_b    = (const float*)d_in[20];
    float* outp = (float*)d_out;

    char* ws = (char*)d_ws;
    size_t off = 0;
    auto alloc = [&](size_t bytes) { void* p = ws + off; off += (bytes + 255) & ~255ULL; return p; };
    _Float16*  feat16 = (_Float16*)alloc((size_t)Bq * Nq * Dq * 2);
    _Float16*  h16    = (_Float16*)alloc((size_t)Bq * Nq * Dq * 2);
    _Float16*  abuf16 = (_Float16*)alloc((size_t)Bq * Nq * Dq * 2);
    _Float16*  pkb    = (_Float16*)alloc(3ull * 64 * Nq * 16 * 2);
    _Float16*  wb     = (_Float16*)alloc(393216ull * 2);
    int*       idx    = (int*)alloc((size_t)Bq * Nq * KNNq * 4);
    float*     part   = (float*)alloc(2048ull * Dq * 4);
    if (off > ws_size) return;

    const _Float16* wip16 = wb;
    const _Float16* wop16 = wb + 98304;
    const _Float16* wl116 = wb + 131072;
    const _Float16* wl216 = wb + 262144;

    int M = Bq * Nq;

    prep_kernel<<<16384 + 1536, 256, 0, stream>>>(x, xyz_w, xyz_b, ohe_w, ohe_b, feat16,
                                                  in_proj_w, out_proj_w, lin1_w, lin2_w, wb);
    knn_kernel<<<dim3(Nq / 64, Bq), 512, 0, stream>>>(x, idx);
    knn_attn_kernel<<<M / 4, 256, 0, stream>>>(feat16, idx, h16);

    for (int l = 0; l < Lq; l++) {
        hgemm_kernel<2><<<dim3(384 / 64, M / 64), 256, 0, stream>>>(
            h16, wip16 + (size_t)l * 384 * 128, in_proj_b + l * 384, pkb, M, 384, 128);
        flash12_kernel<<<dim3(Nq / 128, Bq * Hq), 256, 0, stream>>>(pkb, abuf16);
        if (l == 0) {
            oln_ffn_kernel<0><<<M / 64, 256, 0, stream>>>(
                abuf16, wop16, out_proj_b,
                ln1_w, ln1_b,
                wl116, lin1_b, wl216, lin2_b,
                ln2_w, ln2_b, h16, part);
        } else {
            oln_ffn_kernel<1><<<M / 64, 256, 0, stream>>>(
                abuf16, wop16 + (size_t)l * 128 * 128, out_proj_b + l * 128,
                ln1_w + l * 128, ln1_b + l * 128,
                wl116 + (size_t)l * 512 * 128, lin1_b + l * 512,
                wl216 + (size_t)l * 128 * 512, lin2_b + l * 128,
                ln2_w + l * 128, ln2_b + l * 128, h16, part);
        }
    }

    head_kernel<<<Bq, 512, 0, stream>>>(part, fc1_w, fc1_b, fc2_w, fc2_b, outp);
}